// Round 13
// baseline (45.012 us; speedup 1.0000x reference)
//
#include <hip/hip_runtime.h>

// Problem constants: B=4, N=512, M=512, D=128, H=256, DOUT=128
#define BB    4
#define NN    512
#define MM    512
#define DD    128
#define HH    256
#define DOUTC 128

typedef float v4f __attribute__((ext_vector_type(4)));

// ---------------------------------------------------------------------------
// Kernel 1: precompute (256 blocks x 1024 threads, 16 rows/block)
// Same GEMM as round 10 (measured 4.2 us) but writes TRANSPOSED outputs:
//   AT[b][h][m] = Y[b,m]·W1[0:D,h]          (columns contiguous in m)
//   CT[b][h][n] = X[b,n]·W1[D:2D,h] + b1[h]
// Thread rs owns 4 consecutive rows -> v4f store per h column.
// ---------------------------------------------------------------------------
__global__ __launch_bounds__(1024) void precompute_ac(
    const float* __restrict__ X, const float* __restrict__ Y,
    const float* __restrict__ W1, const float* __restrict__ b1,
    float* __restrict__ AT, float* __restrict__ CT)
{
    __shared__ __align__(16) float rows[16][DD];     // 8 KB
    __shared__ __align__(16) v4f mrg[3][4][4][64];   // 48 KB: [dq-1][rs][r][hq]
    const int bid = blockIdx.x;
    const int t   = threadIdx.x;
    const int isC = bid >> 7;
    const int r0  = (bid & 127) * 16;                // global row (b*512+m)
    const float* src = isC ? X : Y;

    if (t < 512)
        reinterpret_cast<v4f*>(&rows[0][0])[t] =
            reinterpret_cast<const v4f*>(src + (size_t)r0 * DD)[t];
    __syncthreads();

    const int hq = t & 63;            // h-quad
    const int dq = (t >> 6) & 3;      // d-chunk (wave-uniform)
    const int rs = t >> 8;            // row-group (wave-uniform)
    const int d0 = dq * 32;
    const float* wp = W1 + (isC ? DD * HH : 0) + hq * 4;

    v4f acc[4];
#pragma unroll
    for (int r = 0; r < 4; ++r) acc[r] = (v4f){0.f, 0.f, 0.f, 0.f};

#pragma unroll 2
    for (int dg = 0; dg < 32; dg += 4) {
        const int d = d0 + dg;
        const v4f w0 = *reinterpret_cast<const v4f*>(&wp[(d + 0) * HH]);
        const v4f w1 = *reinterpret_cast<const v4f*>(&wp[(d + 1) * HH]);
        const v4f w2 = *reinterpret_cast<const v4f*>(&wp[(d + 2) * HH]);
        const v4f w3 = *reinterpret_cast<const v4f*>(&wp[(d + 3) * HH]);
#pragma unroll
        for (int r = 0; r < 4; ++r) {
            const v4f rv = *reinterpret_cast<const v4f*>(&rows[rs * 4 + r][d]);
            acc[r] += w0 * rv.x;
            acc[r] += w1 * rv.y;
            acc[r] += w2 * rv.z;
            acc[r] += w3 * rv.w;
        }
    }

    if (dq > 0) {
#pragma unroll
        for (int r = 0; r < 4; ++r) mrg[dq - 1][rs][r][hq] = acc[r];
    }
    __syncthreads();
    if (dq == 0) {
#pragma unroll
        for (int r = 0; r < 4; ++r) {
#pragma unroll
            for (int p = 0; p < 3; ++p) acc[r] += mrg[p][rs][r][hq];
        }
        v4f bias = (v4f){0.f, 0.f, 0.f, 0.f};
        if (isC) bias = *reinterpret_cast<const v4f*>(&b1[hq * 4]);
#pragma unroll
        for (int r = 0; r < 4; ++r) acc[r] += bias;

        // transposed store: 4 consecutive m per h column
        const int grow = r0 + rs * 4;        // 4 rows, same batch (r0 % 16 == 0)
        const int bb   = grow >> 9;
        const int mm   = grow & 511;
        float* Tb = isC ? CT : AT;
#pragma unroll
        for (int u = 0; u < 4; ++u) {
            const v4f w = (v4f){acc[0][u], acc[1][u], acc[2][u], acc[3][u]};
            *reinterpret_cast<v4f*>(
                &Tb[((size_t)(bb * HH + hq * 4 + u)) * 512 + mm]) = w;
        }
    }
}

// ---------------------------------------------------------------------------
// Kernel 2: sort + query (256 blocks x 512 threads, 4 columns/block)
// For each column (b,h): bitonic-sort a_m ascending in LDS, inclusive prefix
// scan, then per query n: k = #{a_m < -c} via unrolled binary search and
//   S[b,n,h] = (T - P_k) + (512-k)*c     (= sum_m relu(a_m + c), exact)
// ---------------------------------------------------------------------------
__global__ __launch_bounds__(512) void sort_query(
    const float* __restrict__ AT, const float* __restrict__ CT,
    float* __restrict__ S)
{
    __shared__ float col[4][512];   // sorted values (kept intact)
    __shared__ float t1[4][512];    // scan ping
    __shared__ float t2[4][512];    // scan pong
    const int bid = blockIdx.x;     // 256 = 4 b x 64 h-quads
    const int b   = bid >> 6;
    const int h0  = (bid & 63) * 4;
    const int t   = threadIdx.x;    // 512

    // load 4 A-columns (coalesced per column)
    const float* Abase = AT + ((size_t)(b * HH + h0)) * 512;
#pragma unroll
    for (int u = 0; u < 4; ++u)
        col[u][t] = Abase[(size_t)u * 512 + t];
    __syncthreads();

    // ---- bitonic sort, ascending ----
    for (int k = 2; k <= 512; k <<= 1) {
        for (int j = k >> 1; j > 0; j >>= 1) {
            const int p = t ^ j;
            if (p > t) {
                const bool asc = ((t & k) == 0);
#pragma unroll
                for (int u = 0; u < 4; ++u) {
                    const float x = col[u][t];
                    const float y = col[u][p];
                    if ((x > y) == asc) { col[u][t] = y; col[u][p] = x; }
                }
            }
            __syncthreads();
        }
    }

    // ---- inclusive prefix scan (Hillis-Steele, 9 steps, result in t1) ----
#pragma unroll
    for (int u = 0; u < 4; ++u)
        t1[u][t] = col[u][t] + ((t >= 1) ? col[u][t - 1] : 0.f);
    __syncthreads();
    {
        int d = 2;
#pragma unroll
        for (int s = 0; s < 8; ++s) {
            if ((s & 1) == 0) {          // t1 -> t2
#pragma unroll
                for (int u = 0; u < 4; ++u)
                    t2[u][t] = t1[u][t] + ((t >= d) ? t1[u][t - d] : 0.f);
            } else {                     // t2 -> t1
#pragma unroll
                for (int u = 0; u < 4; ++u)
                    t1[u][t] = t2[u][t] + ((t >= d) ? t2[u][t - d] : 0.f);
            }
            __syncthreads();
            d <<= 1;
        }
    }   // d sequence 1(init),2,4,...,256: 9 steps, odd count -> final in t1

    // ---- queries: thread = n; 4 interleaved binary searches (ILP) ----
    const float* Cbase = CT + ((size_t)(b * HH + h0)) * 512;
    float cv[4], negc[4];
    int kk[4];
#pragma unroll
    for (int u = 0; u < 4; ++u) {
        cv[u]   = Cbase[(size_t)u * 512 + t];   // coalesced
        negc[u] = -cv[u];
        kk[u]   = 0;
    }
#pragma unroll
    for (int step = 512; step > 0; step >>= 1) {
#pragma unroll
        for (int u = 0; u < 4; ++u) {
            const int nk = kk[u] + step;
            if (nk <= 512 && col[u][nk - 1] < negc[u]) kk[u] = nk;
        }
    }

    v4f s4;
#pragma unroll
    for (int u = 0; u < 4; ++u) {
        const float T  = t1[u][511];
        const float Pk = (kk[u] > 0) ? t1[u][kk[u] - 1] : 0.f;
        s4[u] = (T - Pk) + (float)(512 - kk[u]) * cv[u];
    }
    *reinterpret_cast<v4f*>(&S[((size_t)(b * NN + t)) * HH + h0]) = s4;
}

// ---------------------------------------------------------------------------
// Kernel 3: epilogue GEMM (512 blocks x 512 threads, 4 bn-rows/block)
//   out[bn,o] = sum_h S[bn,h]*W2[h,o] + 512*b2[o]     (round-12 phase C logic)
// ---------------------------------------------------------------------------
__global__ __launch_bounds__(512) void epilogue(
    const float* __restrict__ S, const float* __restrict__ W2,
    const float* __restrict__ b2, float* __restrict__ out)
{
    __shared__ __align__(16) float Sl[4][HH];   // 4 KB
    __shared__ __align__(16) v4f red[3 * 128];  // 6 KB
    const int bn0 = blockIdx.x * 4;
    const int t   = threadIdx.x;

    if (t < 256)
        reinterpret_cast<v4f*>(&Sl[0][0])[t] =
            reinterpret_cast<const v4f*>(&S[(size_t)bn0 * HH])[t];
    __syncthreads();

    const int o0 = (t & 31) * 4;       // 128 o
    const int r  = (t >> 5) & 3;       // 4 rows
    const int kq = t >> 7;             // 4 k-quarters of 64
    const int k0 = kq * 64;
    v4f a4 = (v4f){0.f, 0.f, 0.f, 0.f};
    const float* w2p = W2 + o0;
#pragma unroll 4
    for (int k = k0; k < k0 + 64; k += 4) {
        const v4f sv = *reinterpret_cast<const v4f*>(&Sl[r][k]);  // broadcast
        const v4f wA = *reinterpret_cast<const v4f*>(&w2p[(k + 0) * DOUTC]);
        const v4f wB = *reinterpret_cast<const v4f*>(&w2p[(k + 1) * DOUTC]);
        const v4f wC = *reinterpret_cast<const v4f*>(&w2p[(k + 2) * DOUTC]);
        const v4f wD = *reinterpret_cast<const v4f*>(&w2p[(k + 3) * DOUTC]);
        a4 += wA * sv.x;
        a4 += wB * sv.y;
        a4 += wC * sv.z;
        a4 += wD * sv.w;
    }
    if (kq) red[(kq - 1) * 128 + (t & 127)] = a4;
    __syncthreads();
    if (kq == 0) {
#pragma unroll
        for (int p = 0; p < 3; ++p) a4 += red[p * 128 + (t & 127)];
        a4 += 512.f * (*reinterpret_cast<const v4f*>(&b2[o0]));
        *reinterpret_cast<v4f*>(&out[(size_t)(bn0 + r) * DOUTC + o0]) = a4;
    }
}

// ---------------------------------------------------------------------------
extern "C" void kernel_launch(void* const* d_in, const int* in_sizes, int n_in,
                              void* d_out, int out_size, void* d_ws, size_t ws_size,
                              hipStream_t stream) {
    const float* X  = (const float*)d_in[0];
    const float* Y  = (const float*)d_in[1];
    const float* W1 = (const float*)d_in[2];
    const float* b1 = (const float*)d_in[3];
    const float* W2 = (const float*)d_in[4];
    const float* b2 = (const float*)d_in[5];
    float* out = (float*)d_out;

    float* AT = (float*)d_ws;                    // [4][256][512] = 2 MB
    float* CT = AT + (size_t)BB * HH * 512;      // [4][256][512] = 2 MB
    float* S  = CT + (size_t)BB * HH * 512;      // [4][512][256] = 2 MB

    hipLaunchKernelGGL(precompute_ac, dim3(256), dim3(1024), 0, stream,
                       X, Y, W1, b1, AT, CT);
    hipLaunchKernelGGL(sort_query, dim3(256), dim3(512), 0, stream,
                       AT, CT, S);
    hipLaunchKernelGGL(epilogue, dim3(BB * NN / 4), dim3(512), 0, stream,
                       S, W2, b2, out);
}